// Round 1
// baseline (545.553 us; speedup 1.0000x reference)
//
#include <hip/hip_runtime.h>
#include <math.h>

#define B_    32
#define H_    32
#define KVH_  8
#define D_    128
#define S_    2048
#define REP   4            // H_/KVH_
#define PAIRS 256          // B_*KVH_
#define SCALE 0.08838834764831845f

// k_cache/v_cache: [NUM_BLOCKS, 16, KVH, D] flat; row stride per token = KVH*D = 1024 floats.

__global__ __launch_bounds__(256) void pa_main(
    const float* __restrict__ query,
    const float* __restrict__ k_cache,
    const float* __restrict__ v_cache,
    const int*   __restrict__ slot_map,
    const int*   __restrict__ positions,
    float* __restrict__ ws_l,    // [PAIRS*nsplit*4]
    float* __restrict__ ws_acc,  // [PAIRS*nsplit*4*128]
    float* __restrict__ out,     // used when nsplit==1
    int nsplit)
{
    const int pair  = blockIdx.x / nsplit;
    const int split = blockIdx.x % nsplit;
    const int b     = pair >> 3;      // / KVH_
    const int kvh   = pair & 7;
    const int tid   = threadIdx.x;
    const int lane  = tid & 63;
    const int wave  = tid >> 6;
    const int g     = lane & 15;      // dim group: owns dims [4g..4g+3] and [64+4g..64+4g+3]
    const int ts    = lane >> 4;      // token slot within pass (0..3)

    // inv_freq for this lane's 4 freq indices (i = 4g+j), double-precise
    float invf[4];
    #pragma unroll
    for (int j = 0; j < 4; j++)
        invf[j] = (float)exp(-(double)(4*g + j) * (9.210340371976184 / 64.0));

    // ---- q rope (once, precise trig), SCALE folded in ----
    const int posq = positions[b * S_ + (S_ - 1)];
    float ql[4][4], qh[4][4];
    #pragma unroll
    for (int hh = 0; hh < REP; hh++) {
        const float4* qb = (const float4*)(query + (size_t)(b * H_ + kvh * REP + hh) * D_);
        float4 a = qb[g];
        float4 c = qb[16 + g];
        float al[4] = {a.x, a.y, a.z, a.w};
        float ah[4] = {c.x, c.y, c.z, c.w};
        #pragma unroll
        for (int j = 0; j < 4; j++) {
            double fr = (double)posq * exp(-(double)(4*g + j) * (9.210340371976184 / 64.0));
            float cs = (float)cos(fr), sn = (float)sin(fr);
            ql[hh][j] = (al[j] * cs - ah[j] * sn) * SCALE;
            qh[hh][j] = (ah[j] * cs + al[j] * sn) * SCALE;
        }
    }

    const int chunk  = S_ / nsplit;   // tokens per block
    const int wtok   = chunk >> 2;    // tokens per wave
    const int passes = wtok >> 2;     // 4 tokens per pass
    const int t0     = split * chunk + wave * wtok;
    const int bS     = b * S_;

    float acc_lo[4][4] = {};
    float acc_hi[4][4] = {};
    float lsum[4] = {0.f, 0.f, 0.f, 0.f};

    // ---- prefetch pass 0 ----
    int slot = slot_map[bS + t0 + ts];
    int pos  = positions[bS + t0 + ts];
    int sc   = slot < 0 ? 0 : slot;
    const float4* kb = (const float4*)(k_cache + (size_t)(sc >> 4) * 16384 + (size_t)(sc & 15) * 1024 + kvh * 128);
    const float4* vb = (const float4*)(v_cache + (size_t)(sc >> 4) * 16384 + (size_t)(sc & 15) * 1024 + kvh * 128);
    float4 k1 = kb[g], k2 = kb[16 + g], v1 = vb[g], v2 = vb[16 + g];

    for (int i = 0; i < passes; i++) {
        int nslot = 0, npos = 0;
        float4 nk1 = {0,0,0,0}, nk2 = {0,0,0,0}, nv1 = {0,0,0,0}, nv2 = {0,0,0,0};
        const bool more = (i + 1 < passes);
        if (more) {
            const int st = t0 + (i + 1) * 4 + ts;
            nslot = slot_map[bS + st];
            npos  = positions[bS + st];
            const int nsc = nslot < 0 ? 0 : nslot;
            const float4* nkb = (const float4*)(k_cache + (size_t)(nsc >> 4) * 16384 + (size_t)(nsc & 15) * 1024 + kvh * 128);
            const float4* nvb = (const float4*)(v_cache + (size_t)(nsc >> 4) * 16384 + (size_t)(nsc & 15) * 1024 + kvh * 128);
            nk1 = nkb[g]; nk2 = nkb[16 + g]; nv1 = nvb[g]; nv2 = nvb[16 + g];
        }

        // ---- compute current pass ----
        const float m  = (slot >= 0) ? 1.f : 0.f;
        const float pf = (float)pos;
        float kx[4] = {k1.x, k1.y, k1.z, k1.w};
        float ky[4] = {k2.x, k2.y, k2.z, k2.w};
        float vx[4] = {v1.x * m, v1.y * m, v1.z * m, v1.w * m};
        float vy[4] = {v2.x * m, v2.y * m, v2.z * m, v2.w * m};
        float kl[4], kh[4];
        #pragma unroll
        for (int j = 0; j < 4; j++) {
            float fr = pf * invf[j];
            float sn, cs;
            __sincosf(fr, &sn, &cs);
            kl[j] = (kx[j] * cs - ky[j] * sn) * m;
            kh[j] = (ky[j] * cs + kx[j] * sn) * m;
        }

        float p[4];
        #pragma unroll
        for (int hh = 0; hh < 4; hh++) {
            float t = ql[hh][0] * kl[0];
            t += ql[hh][1] * kl[1];
            t += ql[hh][2] * kl[2];
            t += ql[hh][3] * kl[3];
            t += qh[hh][0] * kh[0];
            t += qh[hh][1] * kh[1];
            t += qh[hh][2] * kh[2];
            t += qh[hh][3] * kh[3];
            p[hh] = t;
        }
        #pragma unroll
        for (int hh = 0; hh < 4; hh++) {
            #pragma unroll
            for (int mm = 1; mm < 16; mm <<= 1)
                p[hh] += __shfl_xor(p[hh], mm);
        }
        #pragma unroll
        for (int hh = 0; hh < 4; hh++) {
            const float w = __expf(p[hh]);   // invalid slots: p==0 -> w==1, matches reference
            lsum[hh] += w;
            #pragma unroll
            for (int j = 0; j < 4; j++) {
                acc_lo[hh][j] += w * vx[j];
                acc_hi[hh][j] += w * vy[j];
            }
        }

        slot = nslot; pos = npos;
        k1 = nk1; k2 = nk2; v1 = nv1; v2 = nv2;
    }

    // ---- merge the 4 token slots within the wave ----
    #pragma unroll
    for (int hh = 0; hh < 4; hh++) {
        lsum[hh] += __shfl_xor(lsum[hh], 16);
        lsum[hh] += __shfl_xor(lsum[hh], 32);
        #pragma unroll
        for (int j = 0; j < 4; j++) {
            acc_lo[hh][j] += __shfl_xor(acc_lo[hh][j], 16);
            acc_lo[hh][j] += __shfl_xor(acc_lo[hh][j], 32);
            acc_hi[hh][j] += __shfl_xor(acc_hi[hh][j], 16);
            acc_hi[hh][j] += __shfl_xor(acc_hi[hh][j], 32);
        }
    }

    // ---- merge the 4 waves via LDS ----
    __shared__ float lds_acc[4][4][128];
    __shared__ float lds_l[4][4];
    if (lane < 16) {
        #pragma unroll
        for (int hh = 0; hh < 4; hh++)
            #pragma unroll
            for (int j = 0; j < 4; j++) {
                lds_acc[wave][hh][4*g + j]      = acc_lo[hh][j];
                lds_acc[wave][hh][64 + 4*g + j] = acc_hi[hh][j];
            }
    }
    if (lane == 0) {
        #pragma unroll
        for (int hh = 0; hh < 4; hh++) lds_l[wave][hh] = lsum[hh];
    }
    __syncthreads();

    for (int v = tid; v < 512; v += 256) {
        const int hh = v >> 7, d = v & 127;
        const float a = lds_acc[0][hh][d] + lds_acc[1][hh][d] + lds_acc[2][hh][d] + lds_acc[3][hh][d];
        if (nsplit > 1) {
            ws_acc[((size_t)(pair * nsplit + split) * 4 + hh) * 128 + d] = a;
        } else {
            const float lt = lds_l[0][hh] + lds_l[1][hh] + lds_l[2][hh] + lds_l[3][hh];
            out[((size_t)(b * H_ + kvh * REP + hh)) * D_ + d] = a / lt;
        }
    }
    if (nsplit > 1 && tid < 4) {
        ws_l[(pair * nsplit + split) * 4 + tid] =
            lds_l[0][tid] + lds_l[1][tid] + lds_l[2][tid] + lds_l[3][tid];
    }
}

__global__ __launch_bounds__(512) void pa_reduce(
    const float* __restrict__ ws_l,
    const float* __restrict__ ws_acc,
    float* __restrict__ out,
    int nsplit)
{
    const int pair = blockIdx.x;
    const int b = pair >> 3, kvh = pair & 7;
    const int hh = threadIdx.x >> 7;
    const int d  = threadIdx.x & 127;
    float a = 0.f;
    for (int s = 0; s < nsplit; s++)
        a += ws_acc[((size_t)(pair * nsplit + s) * 4 + hh) * 128 + d];
    float lt = 0.f;
    for (int s = 0; s < nsplit; s++)
        lt += ws_l[(pair * nsplit + s) * 4 + hh];
    out[((size_t)(b * H_ + kvh * REP + hh)) * D_ + d] = a / lt;
}

extern "C" void kernel_launch(void* const* d_in, const int* in_sizes, int n_in,
                              void* d_out, int out_size, void* d_ws, size_t ws_size,
                              hipStream_t stream) {
    const float* query = (const float*)d_in[0];
    const float* kc    = (const float*)d_in[1];
    const float* vc    = (const float*)d_in[2];
    const int*   sm    = (const int*)d_in[3];
    const int*   pos   = (const int*)d_in[4];
    float* out = (float*)d_out;

    int nsplit = 1;
    const int cands[3] = {8, 4, 2};
    for (int c = 0; c < 3; c++) {
        size_t need = (size_t)PAIRS * cands[c] * (4 + 512) * sizeof(float);
        if (ws_size >= need) { nsplit = cands[c]; break; }
    }

    float* ws_l   = (float*)d_ws;
    float* ws_acc = ws_l + (size_t)PAIRS * nsplit * 4;

    pa_main<<<dim3(PAIRS * nsplit), dim3(256), 0, stream>>>(
        query, kc, vc, sm, pos, ws_l, ws_acc, out, nsplit);
    if (nsplit > 1)
        pa_reduce<<<dim3(PAIRS), dim3(512), 0, stream>>>(ws_l, ws_acc, out, nsplit);
}